// Round 12
// baseline (414.354 us; speedup 1.0000x reference)
//
#include <hip/hip_runtime.h>
#include <hip/hip_bf16.h>

#define N_ROWS 262144
#define D_IN 162
#define K_DIM 30
#define ROWS 32          // rows per block

using bf16_t = __hip_bfloat16;
typedef __attribute__((ext_vector_type(8))) short bf16x8;
typedef __attribute__((ext_vector_type(4))) float f32x4;

// byte offset into a swizzled LDS tile: row stride 512 B, col in bf16 elems.
__device__ __forceinline__ int swz_byte(int row, int col) {
  int b = (row << 9) + (col << 1);
  return b ^ ((row & 7) << 4);
}

__device__ __forceinline__ uint32_t bf16b(float x) {
  return (uint32_t)__builtin_bit_cast(unsigned short, __float2bfloat16(x));
}
__device__ __forceinline__ uint32_t pack2(float lo, float hi) {
  return bf16b(lo) | (bf16b(hi) << 16);
}

__device__ __forceinline__ float fexp2(float x) { return __builtin_amdgcn_exp2f(x); }
__device__ __forceinline__ float flog2(float x) { return __builtin_amdgcn_logf(x); }
__device__ __forceinline__ float frcp (float x) { return __builtin_amdgcn_rcpf(x); }

__device__ __forceinline__ float sp_fast(float x) {        // softplus
  float e = fexp2(fabsf(x) * -1.44269504f);
  return fmaxf(x, 0.f) + 0.69314718f * flog2(1.f + e);
}
__device__ __forceinline__ float sigmoid_fast(float x) {
  return frcp(1.f + fexp2(x * -1.44269504f));
}

// pin a value in VGPRs at this program point
template<typename T> __device__ __forceinline__ void pin(T& x) {
  asm volatile("" : "+v"(x));
}

// ---------------- ONE fused weight-pack kernel --------------------------------
// Packs all 5 weight matrices fp32->bf16 into [kb][Np][32] fragment layout in a
// single launch (was 5 serialized launches ~= 10-20us of graph-replay time).
// Layout offsets (bf16 elems): Wp1 0 | Wp2 49152 | Wpab 114688 | Wpd1 131072 |
// Wpd2 139264 | total 188416.
__global__ void pack_all_kernel(const float* __restrict__ W1, const float* __restrict__ W2,
                                const float* __restrict__ Wa, const float* __restrict__ Wb,
                                const float* __restrict__ Wd1, const float* __restrict__ Wd2,
                                bf16_t* __restrict__ ws) {
  int idx = blockIdx.x * 256 + threadIdx.x;
  if (idx >= 188416) return;
  float v = 0.f;
  if (idx < 49152) {                       // Wp1: K=162 N=256 Np=256 KB=6
    int t = idx, ks = t & 31, n = (t >> 5) & 255, kb = t >> 13;
    int k = kb * 32 + ks;
    if (k < 162) v = W1[k * 256 + n];
  } else if (idx < 114688) {               // Wp2: K=256 N=256 Np=256 KB=8
    int t = idx - 49152, ks = t & 31, n = (t >> 5) & 255, kb = t >> 13;
    int k = kb * 32 + ks;
    v = W2[k * 256 + n];
  } else if (idx < 131072) {               // Wpab interleaved: K=256 Np=64 KB=8
    int t = idx - 114688, ks = t & 31, n = (t >> 5) & 63, kb = t >> 11;
    int k = kb * 32 + ks;
    int j = n >> 1, s = n & 1;
    if (j < K_DIM) v = s ? Wb[k * K_DIM + j] : Wa[k * K_DIM + j];
  } else if (idx < 139264) {               // Wpd1: K=30 N=256 Np=256 KB=1
    int t = idx - 131072, ks = t & 31, n = t >> 5;
    if (ks < 30) v = Wd1[ks * 256 + n];
  } else {                                 // Wpd2: K=256 N=162 Np=192 KB=8
    int t = idx - 139264, ks = t & 31, n = (t >> 5) % 192, kb = t / (32 * 192);
    int k = kb * 32 + ks;
    if (n < 162) v = Wd2[k * 162 + n];
  }
  ws[idx] = __float2bfloat16(v);
}

// ---------------- weight fragment load (one kb, NMO out-col groups) -----------
template<int NP, int NMO>
__device__ __forceinline__ void wload(const bf16_t* __restrict__ Wp, int kb, int ocBase,
                                      int lr, int lg, bf16x8 (&out)[NMO]) {
#pragma unroll
  for (int mo = 0; mo < NMO; ++mo)
    out[mo] = *reinterpret_cast<const bf16x8*>(
        Wp + ((kb * NP + ocBase + 16 * mo + lr) << 5) + 8 * lg);
}

// ---------------- swapped-operand GEMM with rolling 2-kb weight prefetch ------
// T5: setprio(1) across the MFMA cluster; co-resident independent blocks give
// the CU scheduler phase diversity to arbitrate (attn-regime, m191).
template<int KB, int NP, int NMO>
__device__ __forceinline__ void gemm_roll(const uint8_t* lds, int srcOff,
                                          const bf16_t* __restrict__ Wp, int ocBase,
                                          int lr, int lg, f32x4 (&acc)[NMO][2],
                                          bf16x8 (&wbuf)[2][NMO]) {
  int bE[2], bO[2];   // even/odd-kb LDS bases (128B pair-steps commute with row-XOR)
#pragma unroll
  for (int nr = 0; nr < 2; ++nr) {
    bE[nr] = srcOff + swz_byte(16 * nr + lr, 8 * lg);
    bO[nr] = srcOff + swz_byte(16 * nr + lr, 32 + 8 * lg);
  }
  __builtin_amdgcn_s_setprio(1);
#pragma unroll
  for (int kb = 0; kb < KB; ++kb) {
    bf16x8 cur[NMO];
#pragma unroll
    for (int mo = 0; mo < NMO; ++mo) cur[mo] = wbuf[kb & 1][mo];
    if (kb + 2 < KB)
      wload<NP, NMO>(Wp, kb + 2, ocBase, lr, lg, wbuf[kb & 1]);
    bf16x8 hf[2];
#pragma unroll
    for (int nr = 0; nr < 2; ++nr) {
      int base = (kb & 1) ? bO[nr] : bE[nr];
      hf[nr] = *reinterpret_cast<const bf16x8*>(lds + base + (kb >> 1) * 128);
    }
#pragma unroll
    for (int mo = 0; mo < NMO; ++mo)
#pragma unroll
      for (int nr = 0; nr < 2; ++nr)
        acc[mo][nr] = __builtin_amdgcn_mfma_f32_16x16x32_bf16(cur[mo], hf[nr], acc[mo][nr], 0, 0, 0);
  }
  __builtin_amdgcn_s_setprio(0);
}

template<int NMO>
__device__ __forceinline__ void acc_bias_init(const float* __restrict__ bias, int ocBase,
                                              int lg, f32x4 (&acc)[NMO][2]) {
#pragma unroll
  for (int mo = 0; mo < NMO; ++mo) {
    float4 bv = *reinterpret_cast<const float4*>(bias + ocBase + 16 * mo + 4 * lg);
    f32x4 t = {bv.x, bv.y, bv.z, bv.w};
#pragma unroll
    for (int nr = 0; nr < 2; ++nr) acc[mo][nr] = t;
  }
}

// relu -> packed bf16x4 -> one ds_write_b64 per fragment
template<int NMO>
__device__ __forceinline__ void epi_relu_store(uint8_t* lds, int dstOff, int ocBase,
                                               int lr, int lg, f32x4 (&acc)[NMO][2]) {
#pragma unroll
  for (int mo = 0; mo < NMO; ++mo)
#pragma unroll
    for (int nr = 0; nr < 2; ++nr) {
      int row = 16 * nr + lr;
      int col = ocBase + 16 * mo + 4 * lg;
      float x0 = fmaxf(acc[mo][nr][0], 0.f), x1 = fmaxf(acc[mo][nr][1], 0.f);
      float x2 = fmaxf(acc[mo][nr][2], 0.f), x3 = fmaxf(acc[mo][nr][3], 0.f);
      uint2 p; p.x = pack2(x0, x1); p.y = pack2(x2, x3);
      *reinterpret_cast<uint2*>(lds + dstOff + swz_byte(row, col)) = p;
    }
}

// ---------------- fused scan + fragment build ---------------------------------
template<int LG>
__device__ __forceinline__ bf16x8 scan_frag(const float* __restrict__ vrow,
                                            float* __restrict__ piOut) {
  float ex = 1.f, hold = 0.f;
  uint32_t pk0 = 0, pk1 = 0, pk2 = 0, pk3 = 0;
#pragma unroll
  for (int j = 0; j < 32; ++j) {
    float pi;
    if (j < K_DIM - 1)       { float vj = vrow[j]; pi = vj * ex; ex *= (1.f - vj); }
    else if (j == K_DIM - 1)   pi = ex;      // v_K forced to 1
    else                       pi = 0.f;     // pad K->32
    if (piOut != nullptr && j < K_DIM) piOut[j] = pi;
    if (j >= 8 * LG && j < 8 * LG + 8) {
      if (j & 1) {
        uint32_t p = pack2(hold, pi);
        switch ((j - 8 * LG) >> 1) {
          case 0: pk0 = p; break; case 1: pk1 = p; break;
          case 2: pk2 = p; break; default: pk3 = p;
        }
      } else hold = pi;
    }
  }
  uint4 t = make_uint4(pk0, pk1, pk2, pk3);
  return __builtin_bit_cast(bf16x8, t);
}

// ---------------- fused forward ------------------------------------------------
// LDS ping-pong: A=[0,16K): Yh -> h2 -> d ; B=[16K,32K): h1 -> {vbuf fp32[32][36]
// at +0, piT fp32[32][34] at +8192}.
#define OFF_B  16384
#define OFF_PI (16384 + 8192)

__launch_bounds__(256, 4)
__global__ void usdn_fused(const float* __restrict__ Yh, const float* __restrict__ u,
                           const float* __restrict__ b1, const float* __restrict__ b2,
                           const float* __restrict__ ba, const float* __restrict__ bb,
                           const float* __restrict__ bd1, const float* __restrict__ bd2,
                           const bf16_t* __restrict__ Wp1, const bf16_t* __restrict__ Wp2,
                           const bf16_t* __restrict__ Wpab, const bf16_t* __restrict__ Wpd1,
                           const bf16_t* __restrict__ Wpd2,
                           float* __restrict__ outRecon, float* __restrict__ outAlpha,
                           float* __restrict__ outBeta, float* __restrict__ outPi) {
  __shared__ __align__(16) uint8_t lds[32768];

  const int tid = threadIdx.x;
  const int w  = tid >> 6;
  const int l  = tid & 63;
  const int lr = l & 15;
  const int lg = l >> 4;
  const int r0 = blockIdx.x * ROWS;

  // ---- stage Yh: global loads to regs, then G1-weight prefetch (pinned), then pack
  const int srow = tid >> 3, sl8 = tid & 7;
  float2 sv[12];
  {
    const float2* src = reinterpret_cast<const float2*>(Yh + (size_t)(r0 + srow) * D_IN);
#pragma unroll
    for (int it = 0; it < 12; ++it) {
      int f2 = sl8 + it * 8;
      if (f2 < 81) sv[it] = src[f2];
    }
  }
  bf16x8 w1buf[2][4];
  wload<256, 4>(Wp1, 0, w * 64, lr, lg, w1buf[0]);
  wload<256, 4>(Wp1, 1, w * 64, lr, lg, w1buf[1]);
#pragma unroll
  for (int mo = 0; mo < 4; ++mo) { pin(w1buf[0][mo]); pin(w1buf[1][mo]); }
  {
#pragma unroll
    for (int it = 0; it < 12; ++it) {
      int f2 = sl8 + it * 8;
      uint32_t p = 0;
      if (f2 < 81) p = pack2(sv[it].x, sv[it].y);
      if (f2 < 96) *reinterpret_cast<uint32_t*>(lds + swz_byte(srow, f2 * 2)) = p;
    }
  }
  __syncthreads();                                   // (1)

  // ---- GEMM1: h1 = relu(W1^T x^T + b1), K=192, A -> B
  bf16x8 w2buf[2][4];
  {
    f32x4 acc[4][2];
    acc_bias_init<4>(b1, w * 64, lg, acc);
    gemm_roll<6, 256, 4>(lds, 0, Wp1, w * 64, lr, lg, acc, w1buf);
    wload<256, 4>(Wp2, 0, w * 64, lr, lg, w2buf[0]);
    wload<256, 4>(Wp2, 1, w * 64, lr, lg, w2buf[1]);
#pragma unroll
    for (int mo = 0; mo < 4; ++mo) { pin(w2buf[0][mo]); pin(w2buf[1][mo]); }
    epi_relu_store<4>(lds, OFF_B, w * 64, lr, lg, acc);
  }
  __syncthreads();                                   // (2)

  // ---- GEMM2: h2 = relu(W2^T h1^T + b2), K=256, B -> A (Yh dead)
  bf16x8 wh[8];
  {
    f32x4 acc[4][2];
    acc_bias_init<4>(b2, w * 64, lg, acc);
    gemm_roll<8, 256, 4>(lds, OFF_B, Wp2, w * 64, lr, lg, acc, w2buf);
#pragma unroll
    for (int kb = 0; kb < 8; ++kb) {
      wh[kb] = *reinterpret_cast<const bf16x8*>(Wpab + ((kb * 64 + 16 * w + lr) << 5) + 8 * lg);
      pin(wh[kb]);
    }
    epi_relu_store<4>(lds, 0, w * 64, lr, lg, acc);
  }
  __syncthreads();                                   // (3)

  // ---- heads: alpha/beta = softplus + eps; v -> vbuf fp32[32][36] (B, h1 dead)
  float regA0[2], regA1[2], regB0[2], regB1[2];
  const int j0 = 8 * w + 2 * lg;
  bf16x8 w4[4];
  bf16x8 w5buf[2][3];
  {
    bool jv = (j0 < K_DIM);
    float ba0 = jv ? ba[j0] : 0.f,     bb0 = jv ? bb[j0] : 0.f;
    float ba1 = jv ? ba[j0 + 1] : 0.f, bb1 = jv ? bb[j0 + 1] : 0.f;
    f32x4 acc[2];
    f32x4 binit = {ba0, bb0, ba1, bb1};
    acc[0] = binit; acc[1] = binit;
    int bE[2], bO[2];
#pragma unroll
    for (int nr = 0; nr < 2; ++nr) {
      bE[nr] = swz_byte(16 * nr + lr, 8 * lg);
      bO[nr] = swz_byte(16 * nr + lr, 32 + 8 * lg);
    }
    __builtin_amdgcn_s_setprio(1);
#pragma unroll
    for (int kb = 0; kb < 8; ++kb) {
#pragma unroll
      for (int nr = 0; nr < 2; ++nr) {
        int base = (kb & 1) ? bO[nr] : bE[nr];
        bf16x8 hf = *reinterpret_cast<const bf16x8*>(lds + base + (kb >> 1) * 128);
        acc[nr] = __builtin_amdgcn_mfma_f32_16x16x32_bf16(wh[kb], hf, acc[nr], 0, 0, 0);
      }
    }
    __builtin_amdgcn_s_setprio(0);
    wload<256, 4>(Wpd1, 0, w * 64, lr, lg, w4);
    wload<192, 3>(Wpd2, 0, 48 * w, lr, lg, w5buf[0]);
    wload<192, 3>(Wpd2, 1, 48 * w, lr, lg, w5buf[1]);
#pragma unroll
    for (int mo = 0; mo < 4; ++mo) pin(w4[mo]);
#pragma unroll
    for (int mo = 0; mo < 3; ++mo) { pin(w5buf[0][mo]); pin(w5buf[1][mo]); }

    float uu  = u[0] * 0.98f + 0.01f;
    float l2u = flog2(uu);
    float* vbuf = reinterpret_cast<float*>(lds + OFF_B);
#pragma unroll
    for (int nr = 0; nr < 2; ++nr) {
      int row = 16 * nr + lr;
      float a0  = sp_fast(acc[nr][0]) + 1e-4f;
      float b0v = sp_fast(acc[nr][1]) + 1e-4f;
      float a1  = sp_fast(acc[nr][2]) + 1e-4f;
      float b1v = sp_fast(acc[nr][3]) + 1e-4f;
      regA0[nr] = a0; regB0[nr] = b0v; regA1[nr] = a1; regB1[nr] = b1v;
      if (jv) {
        if (j0 < K_DIM - 1) {
          float t = fexp2(l2u * frcp(b0v));
          vbuf[row * 36 + j0] = fexp2(flog2(1.f - t) * frcp(a0));
        }
        if (j0 + 1 < K_DIM - 1) {
          float t = fexp2(l2u * frcp(b1v));
          vbuf[row * 36 + j0 + 1] = fexp2(flog2(1.f - t) * frcp(a1));
        }
      }
    }
  }
  __syncthreads();                                   // (4)

  // ---- GEMM4 (scan fused): d = relu(Wd1^T pi^T + bd1) -> A; wave0 writes piT
  {
    f32x4 acc[4][2];
    bf16x8 pf[2];
    const float* vb  = reinterpret_cast<const float*>(lds + OFF_B);
    float* piT = reinterpret_cast<float*>(lds + OFF_PI);
#pragma unroll
    for (int nr = 0; nr < 2; ++nr) {
      int row = 16 * nr + lr;
      const float* vrow = vb + row * 36;
      float* po = (w == 0) ? (piT + row * 34) : nullptr;   // lg==0 branch only
      if      (lg == 0) pf[nr] = scan_frag<0>(vrow, po);
      else if (lg == 1) pf[nr] = scan_frag<1>(vrow, nullptr);
      else if (lg == 2) pf[nr] = scan_frag<2>(vrow, nullptr);
      else              pf[nr] = scan_frag<3>(vrow, nullptr);
    }
    acc_bias_init<4>(bd1, w * 64, lg, acc);
    __builtin_amdgcn_s_setprio(1);
#pragma unroll
    for (int mo = 0; mo < 4; ++mo)
#pragma unroll
      for (int nr = 0; nr < 2; ++nr)
        acc[mo][nr] = __builtin_amdgcn_mfma_f32_16x16x32_bf16(w4[mo], pf[nr], acc[mo][nr], 0, 0, 0);
    __builtin_amdgcn_s_setprio(0);
    epi_relu_store<4>(lds, 0, w * 64, lr, lg, acc);
  }
  __syncthreads();                                   // (5)

  // ---- GEMM5: recon = sigmoid(Wd2^T d^T + bd2); wave w: oc 48w.. (pad 192)
  {
    f32x4 acc[3][2];
#pragma unroll
    for (int mo = 0; mo < 3; ++mo) {
      int col0 = 48 * w + 16 * mo + 4 * lg;
      f32x4 t;
#pragma unroll
      for (int i = 0; i < 4; ++i) t[i] = (col0 + i < D_IN) ? bd2[col0 + i] : 0.f;
#pragma unroll
      for (int nr = 0; nr < 2; ++nr) acc[mo][nr] = t;
    }
    gemm_roll<8, 192, 3>(lds, 0, Wpd2, 48 * w, lr, lg, acc, w5buf);
#pragma unroll
    for (int mo = 0; mo < 3; ++mo) {
      int col0 = 48 * w + 16 * mo + 4 * lg;
#pragma unroll
      for (int nr = 0; nr < 2; ++nr) {
        int row = 16 * nr + lr;
        float s0 = sigmoid_fast(acc[mo][nr][0]);
        float s1 = sigmoid_fast(acc[mo][nr][1]);
        float s2 = sigmoid_fast(acc[mo][nr][2]);
        float s3 = sigmoid_fast(acc[mo][nr][3]);
        float* dst = outRecon + (size_t)(r0 + row) * D_IN + col0;
        if (col0 < D_IN)     *reinterpret_cast<float2*>(dst)     = make_float2(s0, s1);
        if (col0 + 2 < D_IN) *reinterpret_cast<float2*>(dst + 2) = make_float2(s2, s3);
      }
    }
  }

  // ---- deferred global stores (no further barriers) ----
  if (j0 < K_DIM) {
#pragma unroll
    for (int nr = 0; nr < 2; ++nr) {
      int row = 16 * nr + lr;
      size_t base = (size_t)(r0 + row) * K_DIM + j0;
      *reinterpret_cast<float2*>(outAlpha + base) = make_float2(regA0[nr], regA1[nr]);
      *reinterpret_cast<float2*>(outBeta  + base) = make_float2(regB0[nr], regB1[nr]);
    }
  }
  {
    const float* piT = reinterpret_cast<const float*>(lds + OFF_PI);
    int row = tid >> 3, l8 = tid & 7;
#pragma unroll
    for (int half = 0; half < 2; ++half) {
      int f2 = l8 + half * 8;
      if (f2 < 15) {
        float2 pp = *reinterpret_cast<const float2*>(piT + row * 34 + f2 * 2);
        *reinterpret_cast<float2*>(outPi + (size_t)(r0 + row) * K_DIM + f2 * 2) = pp;
      }
    }
  }
}

extern "C" void kernel_launch(void* const* d_in, const int* in_sizes, int n_in,
                              void* d_out, int out_size, void* d_ws, size_t ws_size,
                              hipStream_t stream) {
  const float* Yh  = (const float*)d_in[0];
  const float* u   = (const float*)d_in[1];
  const float* W1  = (const float*)d_in[2];
  const float* b1  = (const float*)d_in[3];
  const float* W2  = (const float*)d_in[4];
  const float* b2  = (const float*)d_in[5];
  const float* Wa  = (const float*)d_in[6];
  const float* ba  = (const float*)d_in[7];
  const float* Wb  = (const float*)d_in[8];
  const float* bb  = (const float*)d_in[9];
  const float* Wd1 = (const float*)d_in[10];
  const float* bd1 = (const float*)d_in[11];
  const float* Wd2 = (const float*)d_in[12];
  const float* bd2 = (const float*)d_in[13];

  bf16_t* ws   = (bf16_t*)d_ws;
  bf16_t* Wp1  = ws;                  // 6*256*32 = 49152 elems
  bf16_t* Wp2  = Wp1 + 49152;         // 8*256*32 = 65536
  bf16_t* Wpab = Wp2 + 65536;         // 8*64*32  = 16384 (interleaved a/b)
  bf16_t* Wpd1 = Wpab + 16384;        // 1*256*32 = 8192
  bf16_t* Wpd2 = Wpd1 + 8192;         // 8*192*32 = 49152

  float* outRecon = (float*)d_out;
  float* outAlpha = outRecon + (size_t)N_ROWS * D_IN;
  float* outBeta  = outAlpha + (size_t)N_ROWS * K_DIM;
  float* outPi    = outBeta  + (size_t)N_ROWS * K_DIM;

  pack_all_kernel<<<736, 256, 0, stream>>>(W1, W2, Wa, Wb, Wd1, Wd2, ws);

  usdn_fused<<<N_ROWS / ROWS, 256, 0, stream>>>(Yh, u, b1, b2, ba, bb, bd1, bd2,
                                                Wp1, Wp2, Wpab, Wpd1, Wpd2,
                                                outRecon, outAlpha, outBeta, outPi);
}

// Round 13
// 267.240 us; speedup vs baseline: 1.5505x; 1.5505x over previous
//
#include <hip/hip_runtime.h>
#include <hip/hip_bf16.h>

#define N_ROWS 262144
#define D_IN 162
#define K_DIM 30
#define ROWS 32          // rows per block

using bf16_t = __hip_bfloat16;
typedef __attribute__((ext_vector_type(8))) short bf16x8;
typedef __attribute__((ext_vector_type(4))) float f32x4;

// byte offset into a swizzled LDS tile: row stride 512 B, col in bf16 elems.
// XOR of (row&7) into byte bits 4-6 spreads 8 consecutive rows across 8
// distinct 16B slots. Buffers using this must have 512 B row stride.
__device__ __forceinline__ int swz_byte(int row, int col) {
  int b = (row << 9) + (col << 1);
  return b ^ ((row & 7) << 4);
}

__device__ __forceinline__ uint32_t bf16b(float x) {
  return (uint32_t)__builtin_bit_cast(unsigned short, __float2bfloat16(x));
}
__device__ __forceinline__ uint32_t pack2(float lo, float hi) {
  return bf16b(lo) | (bf16b(hi) << 16);
}

// single-instruction transcendentals (rel err ~1e-5, vs 2e-2 threshold)
__device__ __forceinline__ float fexp2(float x) { return __builtin_amdgcn_exp2f(x); }
__device__ __forceinline__ float flog2(float x) { return __builtin_amdgcn_logf(x); }
__device__ __forceinline__ float frcp (float x) { return __builtin_amdgcn_rcpf(x); }

__device__ __forceinline__ float sp_fast(float x) {        // softplus
  float e = fexp2(fabsf(x) * -1.44269504f);
  return fmaxf(x, 0.f) + 0.69314718f * flog2(1.f + e);
}
__device__ __forceinline__ float sigmoid_fast(float x) {
  return frcp(1.f + fexp2(x * -1.44269504f));
}

// pin a value in VGPRs at this program point (R6-verified harmless; do NOT
// combine with s_setprio -- R12 showed that combination forces spills)
template<typename T> __device__ __forceinline__ void pin(T& x) {
  asm volatile("" : "+v"(x));
}

// ---------------- ONE fused weight-pack kernel --------------------------------
// Packs all 5 weight matrices fp32->bf16 into [kb][Np][32] fragment layout in a
// single launch (was 5 serialized launches).
// Layout offsets (bf16 elems): Wp1 0 | Wp2 49152 | Wpab 114688 | Wpd1 131072 |
// Wpd2 139264 | total 188416.
__global__ void pack_all_kernel(const float* __restrict__ W1, const float* __restrict__ W2,
                                const float* __restrict__ Wa, const float* __restrict__ Wb,
                                const float* __restrict__ Wd1, const float* __restrict__ Wd2,
                                bf16_t* __restrict__ ws) {
  int idx = blockIdx.x * 256 + threadIdx.x;
  if (idx >= 188416) return;
  float v = 0.f;
  if (idx < 49152) {                       // Wp1: K=162 N=256 Np=256 KB=6
    int t = idx, ks = t & 31, n = (t >> 5) & 255, kb = t >> 13;
    int k = kb * 32 + ks;
    if (k < 162) v = W1[k * 256 + n];
  } else if (idx < 114688) {               // Wp2: K=256 N=256 Np=256 KB=8
    int t = idx - 49152, ks = t & 31, n = (t >> 5) & 255, kb = t >> 13;
    int k = kb * 32 + ks;
    v = W2[k * 256 + n];
  } else if (idx < 131072) {               // Wpab interleaved: K=256 Np=64 KB=8
    int t = idx - 114688, ks = t & 31, n = (t >> 5) & 63, kb = t >> 11;
    int k = kb * 32 + ks;
    int j = n >> 1, s = n & 1;
    if (j < K_DIM) v = s ? Wb[k * K_DIM + j] : Wa[k * K_DIM + j];
  } else if (idx < 139264) {               // Wpd1: K=30 N=256 Np=256 KB=1
    int t = idx - 131072, ks = t & 31, n = t >> 5;
    if (ks < 30) v = Wd1[ks * 256 + n];
  } else {                                 // Wpd2: K=256 N=162 Np=192 KB=8
    int t = idx - 139264, ks = t & 31, n = (t >> 5) % 192, kb = t / (32 * 192);
    int k = kb * 32 + ks;
    if (n < 162) v = Wd2[k * 162 + n];
  }
  ws[idx] = __float2bfloat16(v);
}

// ---------------- weight fragment load (one kb, NMO out-col groups) -----------
template<int NP, int NMO>
__device__ __forceinline__ void wload(const bf16_t* __restrict__ Wp, int kb, int ocBase,
                                      int lr, int lg, bf16x8 (&out)[NMO]) {
#pragma unroll
  for (int mo = 0; mo < NMO; ++mo)
    out[mo] = *reinterpret_cast<const bf16x8*>(
        Wp + ((kb * NP + ocBase + 16 * mo + lr) << 5) + 8 * lg);
}

// ---------------- swapped-operand GEMM with rolling 2-kb weight prefetch ------
template<int KB, int NP, int NMO>
__device__ __forceinline__ void gemm_roll(const uint8_t* lds, int srcOff,
                                          const bf16_t* __restrict__ Wp, int ocBase,
                                          int lr, int lg, f32x4 (&acc)[NMO][2],
                                          bf16x8 (&wbuf)[2][NMO]) {
  int bE[2], bO[2];   // even/odd-kb LDS bases (128B pair-steps commute with row-XOR)
#pragma unroll
  for (int nr = 0; nr < 2; ++nr) {
    bE[nr] = srcOff + swz_byte(16 * nr + lr, 8 * lg);
    bO[nr] = srcOff + swz_byte(16 * nr + lr, 32 + 8 * lg);
  }
#pragma unroll
  for (int kb = 0; kb < KB; ++kb) {
    bf16x8 cur[NMO];
#pragma unroll
    for (int mo = 0; mo < NMO; ++mo) cur[mo] = wbuf[kb & 1][mo];
    if (kb + 2 < KB)
      wload<NP, NMO>(Wp, kb + 2, ocBase, lr, lg, wbuf[kb & 1]);
    bf16x8 hf[2];
#pragma unroll
    for (int nr = 0; nr < 2; ++nr) {
      int base = (kb & 1) ? bO[nr] : bE[nr];
      hf[nr] = *reinterpret_cast<const bf16x8*>(lds + base + (kb >> 1) * 128);
    }
#pragma unroll
    for (int mo = 0; mo < NMO; ++mo)
#pragma unroll
      for (int nr = 0; nr < 2; ++nr)
        acc[mo][nr] = __builtin_amdgcn_mfma_f32_16x16x32_bf16(cur[mo], hf[nr], acc[mo][nr], 0, 0, 0);
  }
}

template<int NMO>
__device__ __forceinline__ void acc_bias_init(const float* __restrict__ bias, int ocBase,
                                              int lg, f32x4 (&acc)[NMO][2]) {
#pragma unroll
  for (int mo = 0; mo < NMO; ++mo) {
    float4 bv = *reinterpret_cast<const float4*>(bias + ocBase + 16 * mo + 4 * lg);
    f32x4 t = {bv.x, bv.y, bv.z, bv.w};
#pragma unroll
    for (int nr = 0; nr < 2; ++nr) acc[mo][nr] = t;
  }
}

// relu -> packed bf16x4 -> one ds_write_b64 per fragment
template<int NMO>
__device__ __forceinline__ void epi_relu_store(uint8_t* lds, int dstOff, int ocBase,
                                               int lr, int lg, f32x4 (&acc)[NMO][2]) {
#pragma unroll
  for (int mo = 0; mo < NMO; ++mo)
#pragma unroll
    for (int nr = 0; nr < 2; ++nr) {
      int row = 16 * nr + lr;
      int col = ocBase + 16 * mo + 4 * lg;
      float x0 = fmaxf(acc[mo][nr][0], 0.f), x1 = fmaxf(acc[mo][nr][1], 0.f);
      float x2 = fmaxf(acc[mo][nr][2], 0.f), x3 = fmaxf(acc[mo][nr][3], 0.f);
      uint2 p; p.x = pack2(x0, x1); p.y = pack2(x2, x3);
      *reinterpret_cast<uint2*>(lds + dstOff + swz_byte(row, col)) = p;
    }
}

// ---------------- fused scan + fragment build ---------------------------------
// Redundant per-lane stick-breaking over one row's v[0..28]; returns the bf16
// MFMA B-fragment for k-window [8*LG, 8*LG+8). If piOut!=null, also writes the
// full fp32 pi row (only wave0/lg0 lanes pass non-null).
template<int LG>
__device__ __forceinline__ bf16x8 scan_frag(const float* __restrict__ vrow,
                                            float* __restrict__ piOut) {
  float ex = 1.f, hold = 0.f;
  uint32_t pk0 = 0, pk1 = 0, pk2 = 0, pk3 = 0;
#pragma unroll
  for (int j = 0; j < 32; ++j) {
    float pi;
    if (j < K_DIM - 1)       { float vj = vrow[j]; pi = vj * ex; ex *= (1.f - vj); }
    else if (j == K_DIM - 1)   pi = ex;      // v_K forced to 1
    else                       pi = 0.f;     // pad K->32
    if (piOut != nullptr && j < K_DIM) piOut[j] = pi;
    if (j >= 8 * LG && j < 8 * LG + 8) {
      if (j & 1) {
        uint32_t p = pack2(hold, pi);
        switch ((j - 8 * LG) >> 1) {         // compile-time in unrolled loop
          case 0: pk0 = p; break; case 1: pk1 = p; break;
          case 2: pk2 = p; break; default: pk3 = p;
        }
      } else hold = pi;
    }
  }
  uint4 t = make_uint4(pk0, pk1, pk2, pk3);
  return __builtin_bit_cast(bf16x8, t);
}

// ---------------- fused forward ------------------------------------------------
// LDS ping-pong: A=[0,16K): Yh -> h2 -> d ; B=[16K,32K): h1 -> {vbuf fp32[32][36]
// at +0, piT fp32[32][34] at +8192}.
#define OFF_B  16384
#define OFF_PI (16384 + 8192)

__launch_bounds__(256, 4)
__global__ void usdn_fused(const float* __restrict__ Yh, const float* __restrict__ u,
                           const float* __restrict__ b1, const float* __restrict__ b2,
                           const float* __restrict__ ba, const float* __restrict__ bb,
                           const float* __restrict__ bd1, const float* __restrict__ bd2,
                           const bf16_t* __restrict__ Wp1, const bf16_t* __restrict__ Wp2,
                           const bf16_t* __restrict__ Wpab, const bf16_t* __restrict__ Wpd1,
                           const bf16_t* __restrict__ Wpd2,
                           float* __restrict__ outRecon, float* __restrict__ outAlpha,
                           float* __restrict__ outBeta, float* __restrict__ outPi) {
  __shared__ __align__(16) uint8_t lds[32768];

  const int tid = threadIdx.x;
  const int w  = tid >> 6;
  const int l  = tid & 63;
  const int lr = l & 15;
  const int lg = l >> 4;
  const int r0 = blockIdx.x * ROWS;

  // ---- stage Yh: global loads to regs, then G1-weight prefetch (pinned), then pack
  const int srow = tid >> 3, sl8 = tid & 7;
  float2 sv[12];
  {
    const float2* src = reinterpret_cast<const float2*>(Yh + (size_t)(r0 + srow) * D_IN);
#pragma unroll
    for (int it = 0; it < 12; ++it) {
      int f2 = sl8 + it * 8;
      if (f2 < 81) sv[it] = src[f2];
    }
  }
  bf16x8 w1buf[2][4];
  wload<256, 4>(Wp1, 0, w * 64, lr, lg, w1buf[0]);
  wload<256, 4>(Wp1, 1, w * 64, lr, lg, w1buf[1]);
#pragma unroll
  for (int mo = 0; mo < 4; ++mo) { pin(w1buf[0][mo]); pin(w1buf[1][mo]); }
  {
#pragma unroll
    for (int it = 0; it < 12; ++it) {
      int f2 = sl8 + it * 8;
      uint32_t p = 0;
      if (f2 < 81) p = pack2(sv[it].x, sv[it].y);
      if (f2 < 96) *reinterpret_cast<uint32_t*>(lds + swz_byte(srow, f2 * 2)) = p;
    }
  }
  __syncthreads();                                   // (1)

  // ---- GEMM1: h1 = relu(W1^T x^T + b1), K=192, A -> B
  bf16x8 w2buf[2][4];
  {
    f32x4 acc[4][2];
    acc_bias_init<4>(b1, w * 64, lg, acc);
    gemm_roll<6, 256, 4>(lds, 0, Wp1, w * 64, lr, lg, acc, w1buf);
    wload<256, 4>(Wp2, 0, w * 64, lr, lg, w2buf[0]);
    wload<256, 4>(Wp2, 1, w * 64, lr, lg, w2buf[1]);
#pragma unroll
    for (int mo = 0; mo < 4; ++mo) { pin(w2buf[0][mo]); pin(w2buf[1][mo]); }
    epi_relu_store<4>(lds, OFF_B, w * 64, lr, lg, acc);
  }
  __syncthreads();                                   // (2)

  // ---- GEMM2: h2 = relu(W2^T h1^T + b2), K=256, B -> A (Yh dead)
  bf16x8 wh[8];
  {
    f32x4 acc[4][2];
    acc_bias_init<4>(b2, w * 64, lg, acc);
    gemm_roll<8, 256, 4>(lds, OFF_B, Wp2, w * 64, lr, lg, acc, w2buf);
#pragma unroll
    for (int kb = 0; kb < 8; ++kb) {
      wh[kb] = *reinterpret_cast<const bf16x8*>(Wpab + ((kb * 64 + 16 * w + lr) << 5) + 8 * lg);
      pin(wh[kb]);
    }
    epi_relu_store<4>(lds, 0, w * 64, lr, lg, acc);
  }
  __syncthreads();                                   // (3)

  // ---- heads: alpha/beta = softplus + eps; v -> vbuf fp32[32][36] (B, h1 dead)
  float regA0[2], regA1[2], regB0[2], regB1[2];
  const int j0 = 8 * w + 2 * lg;
  bf16x8 w4[4];
  bf16x8 w5buf[2][3];
  {
    bool jv = (j0 < K_DIM);
    float ba0 = jv ? ba[j0] : 0.f,     bb0 = jv ? bb[j0] : 0.f;
    float ba1 = jv ? ba[j0 + 1] : 0.f, bb1 = jv ? bb[j0 + 1] : 0.f;
    f32x4 acc[2];
    f32x4 binit = {ba0, bb0, ba1, bb1};
    acc[0] = binit; acc[1] = binit;
    int bE[2], bO[2];
#pragma unroll
    for (int nr = 0; nr < 2; ++nr) {
      bE[nr] = swz_byte(16 * nr + lr, 8 * lg);
      bO[nr] = swz_byte(16 * nr + lr, 32 + 8 * lg);
    }
#pragma unroll
    for (int kb = 0; kb < 8; ++kb) {
#pragma unroll
      for (int nr = 0; nr < 2; ++nr) {
        int base = (kb & 1) ? bO[nr] : bE[nr];
        bf16x8 hf = *reinterpret_cast<const bf16x8*>(lds + base + (kb >> 1) * 128);
        acc[nr] = __builtin_amdgcn_mfma_f32_16x16x32_bf16(wh[kb], hf, acc[nr], 0, 0, 0);
      }
    }
    wload<256, 4>(Wpd1, 0, w * 64, lr, lg, w4);
    wload<192, 3>(Wpd2, 0, 48 * w, lr, lg, w5buf[0]);
    wload<192, 3>(Wpd2, 1, 48 * w, lr, lg, w5buf[1]);
#pragma unroll
    for (int mo = 0; mo < 4; ++mo) pin(w4[mo]);
#pragma unroll
    for (int mo = 0; mo < 3; ++mo) { pin(w5buf[0][mo]); pin(w5buf[1][mo]); }

    float uu  = u[0] * 0.98f + 0.01f;
    float l2u = flog2(uu);
    float* vbuf = reinterpret_cast<float*>(lds + OFF_B);
#pragma unroll
    for (int nr = 0; nr < 2; ++nr) {
      int row = 16 * nr + lr;
      float a0  = sp_fast(acc[nr][0]) + 1e-4f;
      float b0v = sp_fast(acc[nr][1]) + 1e-4f;
      float a1  = sp_fast(acc[nr][2]) + 1e-4f;
      float b1v = sp_fast(acc[nr][3]) + 1e-4f;
      regA0[nr] = a0; regB0[nr] = b0v; regA1[nr] = a1; regB1[nr] = b1v;
      if (jv) {
        if (j0 < K_DIM - 1) {
          float t = fexp2(l2u * frcp(b0v));
          vbuf[row * 36 + j0] = fexp2(flog2(1.f - t) * frcp(a0));
        }
        if (j0 + 1 < K_DIM - 1) {
          float t = fexp2(l2u * frcp(b1v));
          vbuf[row * 36 + j0 + 1] = fexp2(flog2(1.f - t) * frcp(a1));
        }
      }
    }
  }
  __syncthreads();                                   // (4)

  // ---- GEMM4 (scan fused): d = relu(Wd1^T pi^T + bd1) -> A; wave0 writes piT
  {
    f32x4 acc[4][2];
    bf16x8 pf[2];
    const float* vb  = reinterpret_cast<const float*>(lds + OFF_B);
    float* piT = reinterpret_cast<float*>(lds + OFF_PI);
#pragma unroll
    for (int nr = 0; nr < 2; ++nr) {
      int row = 16 * nr + lr;
      const float* vrow = vb + row * 36;
      float* po = (w == 0) ? (piT + row * 34) : nullptr;   // lg==0 branch only
      if      (lg == 0) pf[nr] = scan_frag<0>(vrow, po);
      else if (lg == 1) pf[nr] = scan_frag<1>(vrow, nullptr);
      else if (lg == 2) pf[nr] = scan_frag<2>(vrow, nullptr);
      else              pf[nr] = scan_frag<3>(vrow, nullptr);
    }
    acc_bias_init<4>(bd1, w * 64, lg, acc);
#pragma unroll
    for (int mo = 0; mo < 4; ++mo)
#pragma unroll
      for (int nr = 0; nr < 2; ++nr)
        acc[mo][nr] = __builtin_amdgcn_mfma_f32_16x16x32_bf16(w4[mo], pf[nr], acc[mo][nr], 0, 0, 0);
    epi_relu_store<4>(lds, 0, w * 64, lr, lg, acc);
  }
  __syncthreads();                                   // (5)

  // ---- GEMM5: recon = sigmoid(Wd2^T d^T + bd2); wave w: oc 48w.. (pad 192)
  {
    f32x4 acc[3][2];
#pragma unroll
    for (int mo = 0; mo < 3; ++mo) {
      int col0 = 48 * w + 16 * mo + 4 * lg;
      f32x4 t;
#pragma unroll
      for (int i = 0; i < 4; ++i) t[i] = (col0 + i < D_IN) ? bd2[col0 + i] : 0.f;
#pragma unroll
      for (int nr = 0; nr < 2; ++nr) acc[mo][nr] = t;
    }
    gemm_roll<8, 192, 3>(lds, 0, Wpd2, 48 * w, lr, lg, acc, w5buf);
#pragma unroll
    for (int mo = 0; mo < 3; ++mo) {
      int col0 = 48 * w + 16 * mo + 4 * lg;
#pragma unroll
      for (int nr = 0; nr < 2; ++nr) {
        int row = 16 * nr + lr;
        float s0 = sigmoid_fast(acc[mo][nr][0]);
        float s1 = sigmoid_fast(acc[mo][nr][1]);
        float s2 = sigmoid_fast(acc[mo][nr][2]);
        float s3 = sigmoid_fast(acc[mo][nr][3]);
        float* dst = outRecon + (size_t)(r0 + row) * D_IN + col0;
        if (col0 < D_IN)     *reinterpret_cast<float2*>(dst)     = make_float2(s0, s1);
        if (col0 + 2 < D_IN) *reinterpret_cast<float2*>(dst + 2) = make_float2(s2, s3);
      }
    }
  }

  // ---- deferred global stores (no further barriers) ----
  if (j0 < K_DIM) {
#pragma unroll
    for (int nr = 0; nr < 2; ++nr) {
      int row = 16 * nr + lr;
      size_t base = (size_t)(r0 + row) * K_DIM + j0;
      *reinterpret_cast<float2*>(outAlpha + base) = make_float2(regA0[nr], regA1[nr]);
      *reinterpret_cast<float2*>(outBeta  + base) = make_float2(regB0[nr], regB1[nr]);
    }
  }
  {
    const float* piT = reinterpret_cast<const float*>(lds + OFF_PI);
    int row = tid >> 3, l8 = tid & 7;
#pragma unroll
    for (int half = 0; half < 2; ++half) {
      int f2 = l8 + half * 8;
      if (f2 < 15) {
        float2 pp = *reinterpret_cast<const float2*>(piT + row * 34 + f2 * 2);
        *reinterpret_cast<float2*>(outPi + (size_t)(r0 + row) * K_DIM + f2 * 2) = pp;
      }
    }
  }
}

extern "C" void kernel_launch(void* const* d_in, const int* in_sizes, int n_in,
                              void* d_out, int out_size, void* d_ws, size_t ws_size,
                              hipStream_t stream) {
  const float* Yh  = (const float*)d_in[0];
  const float* u   = (const float*)d_in[1];
  const float* W1  = (const float*)d_in[2];
  const float* b1  = (const float*)d_in[3];
  const float* W2  = (const float*)d_in[4];
  const float* b2  = (const float*)d_in[5];
  const float* Wa  = (const float*)d_in[6];
  const float* ba  = (const float*)d_in[7];
  const float* Wb  = (const float*)d_in[8];
  const float* bb  = (const float*)d_in[9];
  const float* Wd1 = (const float*)d_in[10];
  const float* bd1 = (const float*)d_in[11];
  const float* Wd2 = (const float*)d_in[12];
  const float* bd2 = (const float*)d_in[13];

  bf16_t* ws   = (bf16_t*)d_ws;
  bf16_t* Wp1  = ws;                  // 6*256*32 = 49152 elems
  bf16_t* Wp2  = Wp1 + 49152;         // 8*256*32 = 65536
  bf16_t* Wpab = Wp2 + 65536;         // 8*64*32  = 16384 (interleaved a/b)
  bf16_t* Wpd1 = Wpab + 16384;        // 1*256*32 = 8192
  bf16_t* Wpd2 = Wpd1 + 8192;         // 8*192*32 = 49152

  float* outRecon = (float*)d_out;
  float* outAlpha = outRecon + (size_t)N_ROWS * D_IN;
  float* outBeta  = outAlpha + (size_t)N_ROWS * K_DIM;
  float* outPi    = outBeta  + (size_t)N_ROWS * K_DIM;

  pack_all_kernel<<<736, 256, 0, stream>>>(W1, W2, Wa, Wb, Wd1, Wd2, ws);

  usdn_fused<<<N_ROWS / ROWS, 256, 0, stream>>>(Yh, u, b1, b2, ba, bb, bd1, bd2,
                                                Wp1, Wp2, Wpab, Wpd1, Wpd2,
                                                outRecon, outAlpha, outBeta, outPi);
}